// Round 1
// baseline (528.952 us; speedup 1.0000x reference)
//
#include <hip/hip_runtime.h>
#include <hip/hip_bf16.h>
#include <math.h>

#define NHEADS 12
#define HEAD   64
#define DM     768
#define NB     256
#define SLEN   1024
#define NBATCH 8

typedef __bf16 bf16x8 __attribute__((ext_vector_type(8)));
typedef float  f32x4  __attribute__((ext_vector_type(4)));

// Flag semantics: 1 = inputs are bf16, 0 = inputs are fp32.
__device__ __forceinline__ float gload(const void* p, long i, int bf) {
  return bf ? __bfloat162float(((const __hip_bfloat16*)p)[i])
            : ((const float*)p)[i];
}

// ---------------------------------------------------------------------------
// Detect input dtype. If the buffer holds bf16 N(0,1) data, max|bf16| ~ 4.
// If it holds fp32 data, the interleaved low-mantissa halves read as bf16 have
// uniform-random exponents -> max is astronomically large (w.p. 1 - 1e-60).
// ---------------------------------------------------------------------------
__global__ void detect_dtype(const void* x, int* flag) {
  __shared__ float red[256];
  int t = threadIdx.x;
  const __hip_bfloat16* p = (const __hip_bfloat16*)x;
  float a = fabsf(__bfloat162float(p[t * 2]));
  float b = fabsf(__bfloat162float(p[t * 2 + 1]));
  float m = fmaxf(a, b);
  red[t] = m;
  __syncthreads();
  for (int s = 128; s > 0; s >>= 1) {
    if (t < s) red[t] = fmaxf(red[t], red[t + s]);
    __syncthreads();
  }
  if (t == 0) flag[0] = (red[0] < 1e4f) ? 1 : 0;
}

// Convert any input tensor to a canonical fp32 workspace copy.
__global__ void convertk(const void* __restrict__ src, float* __restrict__ dst,
                         int n, const int* __restrict__ flagp) {
  int bf = flagp[0];
  int i = blockIdx.x * 256 + threadIdx.x;
  if (i < n) dst[i] = gload(src, i, bf);
}

// ---------------------------------------------------------------------------
// Split-bf16 precision scheme: a = ah + al with ah = bf16(a), al = bf16(a-ah).
// a*b ~ ah*bh + ah*bl + al*bh, dropped al*bl term <= 2^-16 relative.
// ---------------------------------------------------------------------------
__global__ __launch_bounds__(256) void split4(
    const void* __restrict__ src, __hip_bfloat16* __restrict__ dh,
    __hip_bfloat16* __restrict__ dl, int n, const int* __restrict__ flagp,
    int use_flag) {
  int bf = use_flag ? flagp[0] : 0;
  int i0 = (blockIdx.x * 256 + threadIdx.x) * 4;
  if (i0 >= n) return;
#pragma unroll
  for (int j = 0; j < 4; j++) {
    float f = gload(src, i0 + j, bf);
    __hip_bfloat16 h = __float2bfloat16(f);
    dh[i0 + j] = h;
    dl[i0 + j] = __float2bfloat16(f - __bfloat162float(h));
  }
}

// Transpose + split: src flagged [R, C] -> dh/dl bf16 [C, R]. 64x64 LDS tiles.
__global__ __launch_bounds__(256) void tsplit(
    const void* __restrict__ src, __hip_bfloat16* __restrict__ dh,
    __hip_bfloat16* __restrict__ dl, int R, int C,
    const int* __restrict__ flagp) {
  int bf = flagp[0];
  __shared__ float t[64][65];
  int r0 = blockIdx.y * 64, c0 = blockIdx.x * 64;
  int cl = threadIdx.x & 63, rl = threadIdx.x >> 6;
#pragma unroll
  for (int i = 0; i < 16; i++) {
    int rr = rl + i * 4;
    t[rr][cl] = gload(src, (long)(r0 + rr) * C + c0 + cl, bf);
  }
  __syncthreads();
#pragma unroll
  for (int i = 0; i < 16; i++) {
    int cc = rl + i * 4;
    float f = t[cl][cc];  // lanes vary cl -> stride 65 -> conflict-free
    __hip_bfloat16 h = __float2bfloat16(f);
    long o = (long)(c0 + cc) * R + r0 + cl;
    dh[o] = h;
    dl[o] = __float2bfloat16(f - __bfloat162float(h));
  }
}

// ---------------------------------------------------------------------------
// MFMA NT GEMM, split-bf16 3-pass: C(z)[m,n] = sum_k A(z)[m,k] * W[n,k].
// Block = 4 waves (2x2), wave tile 64x32 (4x2 frags of 16x16), K-step 32.
// Fragment k-mapping (k = (lane>>4)*8 + elem) is applied IDENTICALLY to A and
// B, so any permutation mismatch vs the true HW k-order cancels. C/D mapping
// is the HW-verified col=lane&15, row=(lane>>4)*4+reg.
// Output offset: z*c_batch + m*om + (n>>6)*oh + (n&63); bf16 when use_flag&&flag.
// ---------------------------------------------------------------------------
#define LOAD_PACK(AH, AL, WH, WL, KO)                                   \
  {                                                                     \
    long _ko = (KO);                                                    \
    _Pragma("unroll") for (int _fi = 0; _fi < 4; _fi++) {               \
      AH[_fi] = *(const bf16x8*)(Abh + aoff[_fi] + _ko);                \
      AL[_fi] = *(const bf16x8*)(Abl + aoff[_fi] + _ko);                \
    }                                                                   \
    _Pragma("unroll") for (int _fj = 0; _fj < 2; _fj++) {               \
      WH[_fj] = *(const bf16x8*)(Wh_g + woff[_fj] + _ko);               \
      WL[_fj] = *(const bf16x8*)(Wl_g + woff[_fj] + _ko);               \
    }                                                                   \
  }

#define MFMA_PACK(AH, AL, WH, WL)                                       \
  {                                                                     \
    _Pragma("unroll") for (int _fi = 0; _fi < 4; _fi++) {               \
      _Pragma("unroll") for (int _fj = 0; _fj < 2; _fj++) {             \
        acc[_fi][_fj] = __builtin_amdgcn_mfma_f32_16x16x32_bf16(        \
            AH[_fi], WH[_fj], acc[_fi][_fj], 0, 0, 0);                  \
        acc[_fi][_fj] = __builtin_amdgcn_mfma_f32_16x16x32_bf16(        \
            AH[_fi], WL[_fj], acc[_fi][_fj], 0, 0, 0);                  \
        acc[_fi][_fj] = __builtin_amdgcn_mfma_f32_16x16x32_bf16(        \
            AL[_fi], WH[_fj], acc[_fi][_fj], 0, 0, 0);                  \
      }                                                                 \
    }                                                                   \
  }

__global__ __launch_bounds__(256) void mfma_nt(
    const __hip_bfloat16* __restrict__ Ah_g, const __hip_bfloat16* __restrict__ Al_g,
    const __hip_bfloat16* __restrict__ Wh_g, const __hip_bfloat16* __restrict__ Wl_g,
    void* __restrict__ Cout, int K, int lda, long a_batch, long c_batch,
    int om, int oh, const int* __restrict__ flagp, int use_flag) {
  int bf = use_flag ? flagp[0] : 0;
  const int lane = threadIdx.x & 63;
  const int wave = threadIdx.x >> 6;
  const int r = lane & 15, g = lane >> 4;
  const int m0 = blockIdx.y * 128 + (wave >> 1) * 64;
  const int n0 = blockIdx.x * 64 + (wave & 1) * 32;
  const int z = blockIdx.z;
  const __hip_bfloat16* Abh = Ah_g + (long)z * a_batch;
  const __hip_bfloat16* Abl = Al_g + (long)z * a_batch;

  long aoff[4], woff[2];
#pragma unroll
  for (int fi = 0; fi < 4; fi++)
    aoff[fi] = (long)(m0 + fi * 16 + r) * lda + g * 8;
#pragma unroll
  for (int fj = 0; fj < 2; fj++)
    woff[fj] = (long)(n0 + fj * 16 + r) * K + g * 8;

  f32x4 zero4 = {0.f, 0.f, 0.f, 0.f};
  f32x4 acc[4][2];
#pragma unroll
  for (int fi = 0; fi < 4; fi++)
#pragma unroll
    for (int fj = 0; fj < 2; fj++) acc[fi][fj] = zero4;

  bf16x8 a0h[4], a0l[4], w0h[2], w0l[2];
  bf16x8 a1h[4], a1l[4], w1h[2], w1l[2];
  const int nk = K >> 5;  // K/32, always even here (24 or 32)
  LOAD_PACK(a0h, a0l, w0h, w0l, 0);
  for (int kt = 0; kt < nk; kt += 2) {
    LOAD_PACK(a1h, a1l, w1h, w1l, (long)(kt + 1) * 32);
    MFMA_PACK(a0h, a0l, w0h, w0l);
    if (kt + 2 < nk) LOAD_PACK(a0h, a0l, w0h, w0l, (long)(kt + 2) * 32);
    MFMA_PACK(a1h, a1l, w1h, w1l);
  }

#pragma unroll
  for (int fi = 0; fi < 4; fi++)
#pragma unroll
    for (int fj = 0; fj < 2; fj++)
#pragma unroll
      for (int v = 0; v < 4; v++) {
        int m = m0 + fi * 16 + g * 4 + v;  // row = (lane>>4)*4 + reg
        int n = n0 + fj * 16 + r;          // col = lane&15
        long off = (long)z * c_batch + (long)m * om + (long)(n >> 6) * oh + (n & 63);
        float val = acc[fi][fj][v];
        if (bf) ((__hip_bfloat16*)Cout)[off] = __float2bfloat16(val);
        else    ((float*)Cout)[off] = val;
      }
}

// ---------------------------------------------------------------------------
// bmu[b,d] = sum_n w_mu[n] * Bmat[n, b*768+d]   (and bsig with w_sigma)
// ---------------------------------------------------------------------------
__global__ __launch_bounds__(256) void bvec(
    const float* __restrict__ Bmat, const float* __restrict__ wmuf,
    const float* __restrict__ wsigf, float* __restrict__ bmu,
    float* __restrict__ bsig) {
  int t = blockIdx.x * 256 + threadIdx.x;
  int w = t / 6144, r = t % 6144;
  const float* wv = w ? wsigf : wmuf;
  float acc = 0.f;
  for (int n = 0; n < NB; n++) acc += wv[n] * Bmat[(long)n * 6144 + r];
  (w ? bsig : bmu)[r] = acc;
}

// kmu[b,c] = sum_d bmu[b,d] * Wk[c,d]   (c = h*64+dh), and ksig with bsig.
__global__ __launch_bounds__(256) void kvec(
    const float* __restrict__ Wkf, const float* __restrict__ bmu,
    const float* __restrict__ bsig, float* __restrict__ kmu,
    float* __restrict__ ksig) {
  int t = blockIdx.x * 256 + threadIdx.x;
  int w = t / 6144, r = t % 6144;
  int b = r / 768, c = r % 768;
  const float* bv = (w ? bsig : bmu) + b * 768;
  const float* wk = Wkf + (long)c * 768;
  float acc = 0.f;
  for (int d = 0; d < 768; d++) acc += bv[d] * wk[d];
  (w ? ksig : kmu)[r] = acc;
}

// wqm[b,h,d] = sum_dh Wq[h*64+dh, d] * kmu[b, h*64+dh]   (and wqs with ksig)
__global__ __launch_bounds__(256) void wqvec(
    const float* __restrict__ Wqf, const float* __restrict__ kmu,
    const float* __restrict__ ksig, float* __restrict__ wqm,
    float* __restrict__ wqs) {
  int t = blockIdx.x * 256 + threadIdx.x;
  int w = t / 73728, r = t % 73728;
  int b = r / 9216, h = (r % 9216) / 768, d = r % 768;
  const float* kv = (w ? ksig : kmu) + b * 768 + h * 64;
  float acc = 0.f;
  for (int dh = 0; dh < 64; dh++)
    acc += Wqf[(long)(h * 64 + dh) * 768 + d] * kv[dh];
  (w ? wqs : wqm)[r] = acc;
}

// ---------------------------------------------------------------------------
// amu[b, hh, qrow] = dot768(q[qrow, b, :], wq{m|s}[b, hh, :]); one wave/q-row.
// ---------------------------------------------------------------------------
__global__ __launch_bounds__(256) void amu_kernel(
    const void* __restrict__ q, const float* __restrict__ wqm,
    const float* __restrict__ wqs, float* __restrict__ amu,
    const int* __restrict__ flagp) {
  int bf = flagp[0];
  int lane = threadIdx.x & 63;
  int wave = threadIdx.x >> 6;
  int qrow = blockIdx.x * 4 + wave;
  int b = blockIdx.y;
  float qv[12];
  long base = ((long)qrow * 8 + b) * 768 + lane;
#pragma unroll
  for (int j = 0; j < 12; j++) qv[j] = gload(q, base + 64 * j, bf);
  for (int hh = 0; hh < 24; hh++) {
    const float* vec = (hh < 12) ? (wqm + ((long)b * 12 + hh) * 768)
                                 : (wqs + ((long)b * 12 + hh - 12) * 768);
    float p = 0.f;
#pragma unroll
    for (int j = 0; j < 12; j++) p += qv[j] * vec[lane + 64 * j];
#pragma unroll
    for (int m = 32; m >= 1; m >>= 1) p += __shfl_xor(p, m);
    if (lane == 0) amu[((long)b * 24 + hh) * 1024 + qrow] = p;
  }
}

// ---------------------------------------------------------------------------
// Fused attention: mu/sigma -> Gaussian basis expectations r -> r . values.
// Writes context directly as split-bf16 (hi/lo) for the final MFMA GEMM.
// ---------------------------------------------------------------------------
__global__ __launch_bounds__(256) void attn(
    const float* __restrict__ values, const float* __restrict__ amu,
    const float* __restrict__ mubf, const float* __restrict__ sigbf,
    __hip_bfloat16* __restrict__ Ch, __hip_bfloat16* __restrict__ Cl) {
  const int b = blockIdx.x, h = blockIdx.y, qc = blockIdx.z;
  const int tid = threadIdx.x;
  const int qrow = qc * 256 + tid;
  __shared__ float s_mub[NB], s_sb2[NB];
  {
    float sb = sigbf[tid];
    s_mub[tid] = mubf[tid];
    s_sb2[tid] = sb * sb;
  }
  __syncthreads();
  float araw = amu[((long)b * 24 + h) * 1024 + qrow] * 0.125f;
  float sraw = amu[((long)b * 24 + 12 + h) * 1024 + qrow] * 0.125f;
  float mu = 1.f / (1.f + expf(-araw));
  float sig = fmaxf(sraw, 0.f) + log1pf(expf(-fabsf(sraw)));  // softplus
  float ctx[HEAD];
#pragma unroll
  for (int d = 0; d < HEAD; d++) ctx[d] = 0.f;
  const float* vp = values + ((long)(b * NHEADS + h)) * NB * HEAD;
  for (int n = 0; n < NB; n++) {
    float inv_s = rsqrtf(s_sb2[n] + sig);
    float t = (mu - s_mub[n]) * inv_s;
    float r = 0.3989422804014327f * inv_s * expf(-0.5f * t * t);
    const float* vrow = vp + n * HEAD;
#pragma unroll
    for (int d = 0; d < HEAD; d++) ctx[d] += r * vrow[d];
  }
  long rowbase = ((long)(b * SLEN + qrow)) * DM + h * HEAD;
#pragma unroll
  for (int d = 0; d < HEAD; d++) {
    float f = ctx[d];
    __hip_bfloat16 hh = __float2bfloat16(f);
    Ch[rowbase + d] = hh;
    Cl[rowbase + d] = __float2bfloat16(f - __bfloat162float(hh));
  }
}

// ---------------------------------------------------------------------------
extern "C" void kernel_launch(void* const* d_in, const int* in_sizes, int n_in,
                              void* d_out, int out_size, void* d_ws, size_t ws_size,
                              hipStream_t stream) {
  const void* x    = d_in[0];
  const void* q    = d_in[1];
  const void* Wq   = d_in[2];
  const void* Wk   = d_in[3];
  const void* Wv   = d_in[4];
  const void* Wo   = d_in[5];
  const void* wmu  = d_in[6];
  const void* wsig = d_in[7];
  const void* mub  = d_in[8];
  const void* sigb = d_in[9];
  const void* G    = d_in[10];

  int* flagp = (int*)d_ws;
  float* base = (float*)d_ws + 16;
  float* Wqf   = base;              // 589824
  float* Wkf   = Wqf + 589824;      // 589824
  float* wmuf  = Wkf + 589824;      // 256
  float* wsigf = wmuf + 256;        // 256
  float* mubf  = wsigf + 256;       // 256
  float* sigbf = mubf + 256;        // 256
  float* Bmat  = sigbf + 256;       // 1572864  [256, 6144] fp32
  float* values= Bmat + 1572864;    // 1572864  [B,H,256,64] fp32
  float* bmu   = values + 1572864;  // 6144
  float* bsig  = bmu + 6144;        // 6144
  float* kmu   = bsig + 6144;       // 6144
  float* ksig  = kmu + 6144;        // 6144
  float* wqm   = ksig + 6144;       // 73728
  float* wqs   = wqm + 73728;       // 73728
  float* amu   = wqs + 73728;       // 196608  [B,24,1024]
  // bf16 arrays (element counts; all 16B-aligned: prefix sums are mult. of 16 floats)
  __hip_bfloat16* Wvh = (__hip_bfloat16*)(amu + 196608);  // 589824
  __hip_bfloat16* Wvl = Wvh + 589824;   // 589824
  __hip_bfloat16* Woh = Wvl + 589824;   // 589824
  __hip_bfloat16* Wol = Woh + 589824;   // 589824
  __hip_bfloat16* Gth = Wol + 589824;   // 262144  [256,1024]
  __hip_bfloat16* Gtl = Gth + 262144;   // 262144
  __hip_bfloat16* Bh  = Gtl + 262144;   // 1572864 [256,6144]
  __hip_bfloat16* Bl  = Bh + 1572864;   // 1572864
  // XCh/XCl: holds x^T [6144,1024] for GEMM1, then reused as ctx-split
  // [8192,768] for GEMM3 (GEMM1 strictly precedes attn on the stream).
  __hip_bfloat16* XCh = Bl + 1572864;   // 6291456
  __hip_bfloat16* XCl = XCh + 6291456;  // 6291456
  // total ~56 MB

  detect_dtype<<<1, 256, 0, stream>>>(x, flagp);

  // fp32 copies needed by the collapse chain
  convertk<<<2304, 256, 0, stream>>>(Wq, Wqf, 589824, flagp);
  convertk<<<2304, 256, 0, stream>>>(Wk, Wkf, 589824, flagp);
  convertk<<<1, 256, 0, stream>>>(wmu, wmuf, 256, flagp);
  convertk<<<1, 256, 0, stream>>>(wsig, wsigf, 256, flagp);
  convertk<<<1, 256, 0, stream>>>(mub, mubf, 256, flagp);
  convertk<<<1, 256, 0, stream>>>(sigb, sigbf, 256, flagp);

  // bf16-split operands for the MFMA GEMMs
  tsplit<<<dim3(4, 16), 256, 0, stream>>>(G, Gth, Gtl, 1024, 256, flagp);
  tsplit<<<dim3(96, 16), 256, 0, stream>>>(x, XCh, XCl, 1024, 6144, flagp);
  split4<<<576, 256, 0, stream>>>(Wv, Wvh, Wvl, 589824, flagp, 1);
  split4<<<576, 256, 0, stream>>>(Wo, Woh, Wol, 589824, flagp, 1);

  // GEMM1: Bmat[m,n] = sum_k Gt[m,k] * Xt[n,k]; M=256 N=6144 K=1024 -> fp32
  mfma_nt<<<dim3(96, 2, 1), 256, 0, stream>>>(
      Gth, Gtl, XCh, XCl, Bmat, /*K=*/1024, /*lda=*/1024,
      /*a_batch=*/0, /*c_batch=*/0, /*om=*/6144, /*oh=*/64, flagp, 0);

  split4<<<1536, 256, 0, stream>>>(Bmat, Bh, Bl, 1572864, flagp, 0);

  // GEMM2: values(z) = Bmat_z @ Wv^T -> [B,H,256,64] fp32
  mfma_nt<<<dim3(12, 2, 8), 256, 0, stream>>>(
      Bh, Bl, Wvh, Wvl, values, /*K=*/768, /*lda=*/6144,
      /*a_batch=*/768, /*c_batch=*/196608, /*om=*/64, /*oh=*/16384, flagp, 0);

  // scores@w collapse chain: bmu/bsig -> kmu/ksig -> wqm/wqs -> amu
  bvec<<<48, 256, 0, stream>>>(Bmat, wmuf, wsigf, bmu, bsig);
  kvec<<<48, 256, 0, stream>>>(Wkf, bmu, bsig, kmu, ksig);
  wqvec<<<576, 256, 0, stream>>>(Wqf, kmu, ksig, wqm, wqs);
  amu_kernel<<<dim3(256, 8), 256, 0, stream>>>(q, wqm, wqs, amu, flagp);

  // fused attention -> ctx split-bf16 [8192,768] (into XCh/XCl)
  attn<<<dim3(8, 12, 4), 256, 0, stream>>>(values, amu, mubf, sigbf, XCh, XCl);

  // GEMM3: out = ctx @ Wo^T; M=8192 N=768 K=768 (store dtype per flag)
  mfma_nt<<<dim3(12, 64, 1), 256, 0, stream>>>(
      XCh, XCl, Woh, Wol, d_out, /*K=*/768, /*lda=*/768,
      /*a_batch=*/0, /*c_batch=*/0, /*om=*/768, /*oh=*/64, flagp, 1);
}

// Round 2
// 499.917 us; speedup vs baseline: 1.0581x; 1.0581x over previous
//
#include <hip/hip_runtime.h>
#include <hip/hip_bf16.h>
#include <math.h>

#define NHEADS 12
#define HEAD   64
#define DM     768
#define NB     256
#define SLEN   1024
#define NBATCH 8

typedef __bf16 bf16x8 __attribute__((ext_vector_type(8)));
typedef float  f32x4  __attribute__((ext_vector_type(4)));

// Flag semantics: 1 = inputs are bf16, 0 = inputs are fp32.
__device__ __forceinline__ float gload(const void* p, long i, int bf) {
  return bf ? __bfloat162float(((const __hip_bfloat16*)p)[i])
            : ((const float*)p)[i];
}

// ---------------------------------------------------------------------------
// Detect input dtype. If the buffer holds bf16 N(0,1) data, max|bf16| ~ 4.
// If it holds fp32 data, the interleaved low-mantissa halves read as bf16 have
// uniform-random exponents -> max is astronomically large (w.p. 1 - 1e-60).
// ---------------------------------------------------------------------------
__global__ void detect_dtype(const void* x, int* flag) {
  __shared__ float red[256];
  int t = threadIdx.x;
  const __hip_bfloat16* p = (const __hip_bfloat16*)x;
  float a = fabsf(__bfloat162float(p[t * 2]));
  float b = fabsf(__bfloat162float(p[t * 2 + 1]));
  float m = fmaxf(a, b);
  red[t] = m;
  __syncthreads();
  for (int s = 128; s > 0; s >>= 1) {
    if (t < s) red[t] = fmaxf(red[t], red[t + s]);
    __syncthreads();
  }
  if (t == 0) flag[0] = (red[0] < 1e4f) ? 1 : 0;
}

// Convert any input tensor to a canonical fp32 workspace copy.
__global__ void convertk(const void* __restrict__ src, float* __restrict__ dst,
                         int n, const int* __restrict__ flagp) {
  int bf = flagp[0];
  int i = blockIdx.x * 256 + threadIdx.x;
  if (i < n) dst[i] = gload(src, i, bf);
}

// ---------------------------------------------------------------------------
// Split-bf16 precision scheme: a = ah + al with ah = bf16(a), al = bf16(a-ah).
// a*b ~ ah*bh + ah*bl + al*bh, dropped al*bl term <= 2^-16 relative.
// ---------------------------------------------------------------------------
__global__ __launch_bounds__(256) void split4(
    const void* __restrict__ src, __hip_bfloat16* __restrict__ dh,
    __hip_bfloat16* __restrict__ dl, int n, const int* __restrict__ flagp,
    int use_flag) {
  int bf = use_flag ? flagp[0] : 0;
  int i0 = (blockIdx.x * 256 + threadIdx.x) * 4;
  if (i0 >= n) return;
#pragma unroll
  for (int j = 0; j < 4; j++) {
    float f = gload(src, i0 + j, bf);
    __hip_bfloat16 h = __float2bfloat16(f);
    dh[i0 + j] = h;
    dl[i0 + j] = __float2bfloat16(f - __bfloat162float(h));
  }
}

// Transpose + split: src flagged [R, C] -> dh/dl bf16 [C, R]. 64x64 LDS tiles.
__global__ __launch_bounds__(256) void tsplit(
    const void* __restrict__ src, __hip_bfloat16* __restrict__ dh,
    __hip_bfloat16* __restrict__ dl, int R, int C,
    const int* __restrict__ flagp) {
  int bf = flagp[0];
  __shared__ float t[64][65];
  int r0 = blockIdx.y * 64, c0 = blockIdx.x * 64;
  int cl = threadIdx.x & 63, rl = threadIdx.x >> 6;
#pragma unroll
  for (int i = 0; i < 16; i++) {
    int rr = rl + i * 4;
    t[rr][cl] = gload(src, (long)(r0 + rr) * C + c0 + cl, bf);
  }
  __syncthreads();
#pragma unroll
  for (int i = 0; i < 16; i++) {
    int cc = rl + i * 4;
    float f = t[cl][cc];  // lanes vary cl -> stride 65 -> conflict-free
    __hip_bfloat16 h = __float2bfloat16(f);
    long o = (long)(c0 + cc) * R + r0 + cl;
    dh[o] = h;
    dl[o] = __float2bfloat16(f - __bfloat162float(h));
  }
}

// ---------------------------------------------------------------------------
// LDS-staged MFMA NT GEMM (m97 structure), split-bf16 3-pass folded into the
// K loop: pass 0 = Ah*Bh, pass 1 = Ah*Bl, pass 2 = Al*Bh.
// Block = 4 waves (2x2), tile 128x128, wave tile 64x64 (4x4 frags), BK=32.
// Staging via global_load_lds width-16: LDS dest is wave-uniform base +
// lane*16 (linear layout, required), global source is per-lane.
// C/D mapping: col=lane&15, row=(lane>>4)*4+reg (HW-verified).
// Output offset: z*c_batch + m*om + (n>>6)*oh + (n&63); bf16 if use_flag&&flag.
// ---------------------------------------------------------------------------
__device__ __forceinline__ void stage_tile(
    const __hip_bfloat16* __restrict__ src, int ld, __hip_bfloat16* lds, int t) {
  int row = t >> 2;
  int col = (t & 3) * 8;
  int wavebase = (t >> 6) * 1024;  // bytes
#pragma unroll
  for (int i = 0; i < 2; i++) {
    const __hip_bfloat16* gp = src + (long)(i * 64 + row) * ld + col;
    __builtin_amdgcn_global_load_lds(
        (const __attribute__((address_space(1))) void*)gp,
        (__attribute__((address_space(3))) void*)((char*)lds + i * 4096 + wavebase),
        16, 0, 0);
  }
}

__global__ __launch_bounds__(256) void mfma_nt_lds(
    const __hip_bfloat16* __restrict__ Ah_g, const __hip_bfloat16* __restrict__ Al_g,
    const __hip_bfloat16* __restrict__ Wh_g, const __hip_bfloat16* __restrict__ Wl_g,
    void* __restrict__ Cout, int K, int lda, int ldb, long a_batch, long c_batch,
    int om, int oh, const int* __restrict__ flagp, int use_flag) {
  int bf = use_flag ? flagp[0] : 0;
  __shared__ __hip_bfloat16 As[128 * 32];
  __shared__ __hip_bfloat16 Bs[128 * 32];

  // Bijective XCD-aware swizzle over the flattened grid (nwg % 8 == 0 for all
  // launches here: 96 / 96 / 384).
  const int gx = gridDim.x, gy = gridDim.y;
  const int nwg = gx * gy * gridDim.z;
  const int lin = (blockIdx.z * gy + blockIdx.y) * gx + blockIdx.x;
  const int swz = (lin & 7) * (nwg >> 3) + (lin >> 3);
  const int bx = swz % gx;
  const int rem = swz / gx;
  const int by = rem % gy;
  const int bz = rem / gy;

  const int m0 = by * 128, n0 = bx * 128;
  const int t = threadIdx.x;
  const int lane = t & 63;
  const int r = lane & 15, g = lane >> 4;
  const int wave = t >> 6;
  const int wm = (wave >> 1) * 64, wn = (wave & 1) * 64;

  const __hip_bfloat16* Abh = Ah_g + (long)bz * a_batch;
  const __hip_bfloat16* Abl = Al_g + (long)bz * a_batch;

  f32x4 zero4 = {0.f, 0.f, 0.f, 0.f};
  f32x4 acc[4][4];
#pragma unroll
  for (int fi = 0; fi < 4; fi++)
#pragma unroll
    for (int fj = 0; fj < 4; fj++) acc[fi][fj] = zero4;

  for (int pass = 0; pass < 3; pass++) {
    const __hip_bfloat16* Ab = (pass < 2) ? Abh : Abl;
    const __hip_bfloat16* Bb = (pass == 1) ? Wl_g : Wh_g;
    const __hip_bfloat16* Arow = Ab + (long)m0 * lda;
    const __hip_bfloat16* Brow = Bb + (long)n0 * ldb;
    for (int k0 = 0; k0 < K; k0 += 32) {
      stage_tile(Arow + k0, lda, As, t);
      stage_tile(Brow + k0, ldb, Bs, t);
      __syncthreads();  // drains vmcnt(0) before barrier (compiler-enforced)
      bf16x8 af[4], bw[4];
#pragma unroll
      for (int fi = 0; fi < 4; fi++)
        af[fi] = *(const bf16x8*)(As + (wm + fi * 16 + r) * 32 + g * 8);
#pragma unroll
      for (int fj = 0; fj < 4; fj++)
        bw[fj] = *(const bf16x8*)(Bs + (wn + fj * 16 + r) * 32 + g * 8);
#pragma unroll
      for (int fi = 0; fi < 4; fi++)
#pragma unroll
        for (int fj = 0; fj < 4; fj++)
          acc[fi][fj] = __builtin_amdgcn_mfma_f32_16x16x32_bf16(
              af[fi], bw[fj], acc[fi][fj], 0, 0, 0);
      __syncthreads();  // protect LDS before next stage overwrites
    }
  }

#pragma unroll
  for (int fi = 0; fi < 4; fi++)
#pragma unroll
    for (int fj = 0; fj < 4; fj++)
#pragma unroll
      for (int v = 0; v < 4; v++) {
        int m = m0 + wm + fi * 16 + g * 4 + v;  // row = (lane>>4)*4 + reg
        int n = n0 + wn + fj * 16 + r;          // col = lane&15
        long off = (long)bz * c_batch + (long)m * om + (long)(n >> 6) * oh + (n & 63);
        float val = acc[fi][fj][v];
        if (bf) ((__hip_bfloat16*)Cout)[off] = __float2bfloat16(val);
        else    ((float*)Cout)[off] = val;
      }
}

// ---------------------------------------------------------------------------
// bmu[b,d] = sum_n w_mu[n] * Bmat[n, b*768+d]   (and bsig with w_sigma)
// ---------------------------------------------------------------------------
__global__ __launch_bounds__(256) void bvec(
    const float* __restrict__ Bmat, const float* __restrict__ wmuf,
    const float* __restrict__ wsigf, float* __restrict__ bmu,
    float* __restrict__ bsig) {
  int t = blockIdx.x * 256 + threadIdx.x;
  int w = t / 6144, r = t % 6144;
  const float* wv = w ? wsigf : wmuf;
  float acc = 0.f;
  for (int n = 0; n < NB; n++) acc += wv[n] * Bmat[(long)n * 6144 + r];
  (w ? bsig : bmu)[r] = acc;
}

// kmu[b,c] = sum_d bmu[b,d] * Wk[c,d]   (c = h*64+dh), and ksig with bsig.
__global__ __launch_bounds__(256) void kvec(
    const float* __restrict__ Wkf, const float* __restrict__ bmu,
    const float* __restrict__ bsig, float* __restrict__ kmu,
    float* __restrict__ ksig) {
  int t = blockIdx.x * 256 + threadIdx.x;
  int w = t / 6144, r = t % 6144;
  int b = r / 768, c = r % 768;
  const float* bv = (w ? bsig : bmu) + b * 768;
  const float* wk = Wkf + (long)c * 768;
  float acc = 0.f;
  for (int d = 0; d < 768; d++) acc += bv[d] * wk[d];
  (w ? ksig : kmu)[r] = acc;
}

// wqm[b,h,d] = sum_dh Wq[h*64+dh, d] * kmu[b, h*64+dh]   (and wqs with ksig)
__global__ __launch_bounds__(256) void wqvec(
    const float* __restrict__ Wqf, const float* __restrict__ kmu,
    const float* __restrict__ ksig, float* __restrict__ wqm,
    float* __restrict__ wqs) {
  int t = blockIdx.x * 256 + threadIdx.x;
  int w = t / 73728, r = t % 73728;
  int b = r / 9216, h = (r % 9216) / 768, d = r % 768;
  const float* kv = (w ? ksig : kmu) + b * 768 + h * 64;
  float acc = 0.f;
  for (int dh = 0; dh < 64; dh++)
    acc += Wqf[(long)(h * 64 + dh) * 768 + d] * kv[dh];
  (w ? wqs : wqm)[r] = acc;
}

// ---------------------------------------------------------------------------
// amu[b, hh, qrow] = dot768(q[qrow, b, :], wq{m|s}[b, hh, :]); one wave/q-row.
// ---------------------------------------------------------------------------
__global__ __launch_bounds__(256) void amu_kernel(
    const void* __restrict__ q, const float* __restrict__ wqm,
    const float* __restrict__ wqs, float* __restrict__ amu,
    const int* __restrict__ flagp) {
  int bf = flagp[0];
  int lane = threadIdx.x & 63;
  int wave = threadIdx.x >> 6;
  int qrow = blockIdx.x * 4 + wave;
  int b = blockIdx.y;
  float qv[12];
  long base = ((long)qrow * 8 + b) * 768 + lane;
#pragma unroll
  for (int j = 0; j < 12; j++) qv[j] = gload(q, base + 64 * j, bf);
  for (int hh = 0; hh < 24; hh++) {
    const float* vec = (hh < 12) ? (wqm + ((long)b * 12 + hh) * 768)
                                 : (wqs + ((long)b * 12 + hh - 12) * 768);
    float p = 0.f;
#pragma unroll
    for (int j = 0; j < 12; j++) p += qv[j] * vec[lane + 64 * j];
#pragma unroll
    for (int m = 32; m >= 1; m >>= 1) p += __shfl_xor(p, m);
    if (lane == 0) amu[((long)b * 24 + hh) * 1024 + qrow] = p;
  }
}

// ---------------------------------------------------------------------------
// Fused attention: mu/sigma -> Gaussian basis expectations r -> r . values.
// Writes context directly as split-bf16 (hi/lo) for the final MFMA GEMM.
// ---------------------------------------------------------------------------
__global__ __launch_bounds__(256) void attn(
    const float* __restrict__ values, const float* __restrict__ amu,
    const float* __restrict__ mubf, const float* __restrict__ sigbf,
    __hip_bfloat16* __restrict__ Ch, __hip_bfloat16* __restrict__ Cl) {
  const int b = blockIdx.x, h = blockIdx.y, qc = blockIdx.z;
  const int tid = threadIdx.x;
  const int qrow = qc * 256 + tid;
  __shared__ float s_mub[NB], s_sb2[NB];
  {
    float sb = sigbf[tid];
    s_mub[tid] = mubf[tid];
    s_sb2[tid] = sb * sb;
  }
  __syncthreads();
  float araw = amu[((long)b * 24 + h) * 1024 + qrow] * 0.125f;
  float sraw = amu[((long)b * 24 + 12 + h) * 1024 + qrow] * 0.125f;
  float mu = 1.f / (1.f + expf(-araw));
  float sig = fmaxf(sraw, 0.f) + log1pf(expf(-fabsf(sraw)));  // softplus
  float ctx[HEAD];
#pragma unroll
  for (int d = 0; d < HEAD; d++) ctx[d] = 0.f;
  const float* vp = values + ((long)(b * NHEADS + h)) * NB * HEAD;
  for (int n = 0; n < NB; n++) {
    float inv_s = rsqrtf(s_sb2[n] + sig);
    float t = (mu - s_mub[n]) * inv_s;
    float r = 0.3989422804014327f * inv_s * expf(-0.5f * t * t);
    const float* vrow = vp + n * HEAD;
#pragma unroll
    for (int d = 0; d < HEAD; d++) ctx[d] += r * vrow[d];
  }
  long rowbase = ((long)(b * SLEN + qrow)) * DM + h * HEAD;
#pragma unroll
  for (int d = 0; d < HEAD; d++) {
    float f = ctx[d];
    __hip_bfloat16 hh = __float2bfloat16(f);
    Ch[rowbase + d] = hh;
    Cl[rowbase + d] = __float2bfloat16(f - __bfloat162float(hh));
  }
}

// ---------------------------------------------------------------------------
extern "C" void kernel_launch(void* const* d_in, const int* in_sizes, int n_in,
                              void* d_out, int out_size, void* d_ws, size_t ws_size,
                              hipStream_t stream) {
  const void* x    = d_in[0];
  const void* q    = d_in[1];
  const void* Wq   = d_in[2];
  const void* Wk   = d_in[3];
  const void* Wv   = d_in[4];
  const void* Wo   = d_in[5];
  const void* wmu  = d_in[6];
  const void* wsig = d_in[7];
  const void* mub  = d_in[8];
  const void* sigb = d_in[9];
  const void* G    = d_in[10];

  int* flagp = (int*)d_ws;
  float* base = (float*)d_ws + 16;
  float* Wqf   = base;              // 589824
  float* Wkf   = Wqf + 589824;      // 589824
  float* wmuf  = Wkf + 589824;      // 256
  float* wsigf = wmuf + 256;        // 256
  float* mubf  = wsigf + 256;       // 256
  float* sigbf = mubf + 256;        // 256
  float* Bmat  = sigbf + 256;       // 1572864  [256, 6144] fp32
  float* values= Bmat + 1572864;    // 1572864  [B,H,256,64] fp32
  float* bmu   = values + 1572864;  // 6144
  float* bsig  = bmu + 6144;        // 6144
  float* kmu   = bsig + 6144;       // 6144
  float* ksig  = kmu + 6144;        // 6144
  float* wqm   = ksig + 6144;       // 73728
  float* wqs   = wqm + 73728;       // 73728
  float* amu   = wqs + 73728;       // 196608  [B,24,1024]
  // bf16 arrays (element counts; all 16B-aligned: prefix sums are mult. of 16 floats)
  __hip_bfloat16* Wvh = (__hip_bfloat16*)(amu + 196608);  // 589824
  __hip_bfloat16* Wvl = Wvh + 589824;   // 589824
  __hip_bfloat16* Woh = Wvl + 589824;   // 589824
  __hip_bfloat16* Wol = Woh + 589824;   // 589824
  __hip_bfloat16* Gth = Wol + 589824;   // 262144  [256,1024]
  __hip_bfloat16* Gtl = Gth + 262144;   // 262144
  __hip_bfloat16* Bh  = Gtl + 262144;   // 1572864 [256,6144]
  __hip_bfloat16* Bl  = Bh + 1572864;   // 1572864
  // XCh/XCl: holds x^T [6144,1024] for GEMM1, then reused as ctx-split
  // [8192,768] for GEMM3 (GEMM1 strictly precedes attn on the stream).
  __hip_bfloat16* XCh = Bl + 1572864;   // 6291456
  __hip_bfloat16* XCl = XCh + 6291456;  // 6291456
  // total ~56 MB

  detect_dtype<<<1, 256, 0, stream>>>(x, flagp);

  // fp32 copies needed by the collapse chain
  convertk<<<2304, 256, 0, stream>>>(Wq, Wqf, 589824, flagp);
  convertk<<<2304, 256, 0, stream>>>(Wk, Wkf, 589824, flagp);
  convertk<<<1, 256, 0, stream>>>(wmu, wmuf, 256, flagp);
  convertk<<<1, 256, 0, stream>>>(wsig, wsigf, 256, flagp);
  convertk<<<1, 256, 0, stream>>>(mub, mubf, 256, flagp);
  convertk<<<1, 256, 0, stream>>>(sigb, sigbf, 256, flagp);

  // bf16-split operands for the MFMA GEMMs
  tsplit<<<dim3(4, 16), 256, 0, stream>>>(G, Gth, Gtl, 1024, 256, flagp);
  tsplit<<<dim3(96, 16), 256, 0, stream>>>(x, XCh, XCl, 1024, 6144, flagp);
  split4<<<576, 256, 0, stream>>>(Wv, Wvh, Wvl, 589824, flagp, 1);
  split4<<<576, 256, 0, stream>>>(Wo, Woh, Wol, 589824, flagp, 1);

  // GEMM1: Bmat[m,n] = sum_k Gt[m,k] * Xt[n,k]; M=256 N=6144 K=1024 -> fp32
  mfma_nt_lds<<<dim3(48, 2, 1), 256, 0, stream>>>(
      Gth, Gtl, XCh, XCl, Bmat, /*K=*/1024, /*lda=*/1024, /*ldb=*/1024,
      /*a_batch=*/0, /*c_batch=*/0, /*om=*/6144, /*oh=*/64, flagp, 0);

  split4<<<1536, 256, 0, stream>>>(Bmat, Bh, Bl, 1572864, flagp, 0);

  // GEMM2: values(z) = Bmat_z @ Wv^T -> [B,H,256,64] fp32
  mfma_nt_lds<<<dim3(6, 2, 8), 256, 0, stream>>>(
      Bh, Bl, Wvh, Wvl, values, /*K=*/768, /*lda=*/6144, /*ldb=*/768,
      /*a_batch=*/768, /*c_batch=*/196608, /*om=*/64, /*oh=*/16384, flagp, 0);

  // scores@w collapse chain: bmu/bsig -> kmu/ksig -> wqm/wqs -> amu
  bvec<<<48, 256, 0, stream>>>(Bmat, wmuf, wsigf, bmu, bsig);
  kvec<<<48, 256, 0, stream>>>(Wkf, bmu, bsig, kmu, ksig);
  wqvec<<<576, 256, 0, stream>>>(Wqf, kmu, ksig, wqm, wqs);
  amu_kernel<<<dim3(256, 8), 256, 0, stream>>>(q, wqm, wqs, amu, flagp);

  // fused attention -> ctx split-bf16 [8192,768] (into XCh/XCl)
  attn<<<dim3(8, 12, 4), 256, 0, stream>>>(values, amu, mubf, sigbf, XCh, XCl);

  // GEMM3: out = ctx @ Wo^T; M=8192 N=768 K=768 (store dtype per flag)
  mfma_nt_lds<<<dim3(6, 64, 1), 256, 0, stream>>>(
      XCh, XCl, Woh, Wol, d_out, /*K=*/768, /*lda=*/768, /*ldb=*/768,
      /*a_batch=*/0, /*c_batch=*/0, /*om=*/768, /*oh=*/64, flagp, 1);
}

// Round 3
// 433.785 us; speedup vs baseline: 1.2194x; 1.1525x over previous
//
#include <hip/hip_runtime.h>
#include <hip/hip_bf16.h>
#include <math.h>

#define NHEADS 12
#define HEAD   64
#define DM     768
#define NB     256
#define SLEN   1024
#define NBATCH 8

typedef __bf16 bf16x8 __attribute__((ext_vector_type(8)));
typedef float  f32x4  __attribute__((ext_vector_type(4)));

// Flag semantics: 1 = inputs are bf16, 0 = inputs are fp32.
__device__ __forceinline__ float gload(const void* p, long i, int bf) {
  return bf ? __bfloat162float(((const __hip_bfloat16*)p)[i])
            : ((const float*)p)[i];
}

// ---------------------------------------------------------------------------
// Detect input dtype. If the buffer holds bf16 N(0,1) data, max|bf16| ~ 4.
// If it holds fp32 data, the interleaved low-mantissa halves read as bf16 have
// uniform-random exponents -> max is astronomically large (w.p. 1 - 1e-60).
// ---------------------------------------------------------------------------
__global__ void detect_dtype(const void* x, int* flag) {
  __shared__ float red[256];
  int t = threadIdx.x;
  const __hip_bfloat16* p = (const __hip_bfloat16*)x;
  float a = fabsf(__bfloat162float(p[t * 2]));
  float b = fabsf(__bfloat162float(p[t * 2 + 1]));
  float m = fmaxf(a, b);
  red[t] = m;
  __syncthreads();
  for (int s = 128; s > 0; s >>= 1) {
    if (t < s) red[t] = fmaxf(red[t], red[t + s]);
    __syncthreads();
  }
  if (t == 0) flag[0] = (red[0] < 1e4f) ? 1 : 0;
}

// Convert any input tensor to a canonical fp32 workspace copy.
__global__ void convertk(const void* __restrict__ src, float* __restrict__ dst,
                         int n, const int* __restrict__ flagp) {
  int bf = flagp[0];
  int i = blockIdx.x * 256 + threadIdx.x;
  if (i < n) dst[i] = gload(src, i, bf);
}

// ---------------------------------------------------------------------------
// Split-bf16 precision scheme: a = ah + al with ah = bf16(a), al = bf16(a-ah).
// a*b ~ ah*bh + ah*bl + al*bh, dropped al*bl term <= 2^-16 relative.
// ---------------------------------------------------------------------------
__global__ __launch_bounds__(256) void split4(
    const void* __restrict__ src, __hip_bfloat16* __restrict__ dh,
    __hip_bfloat16* __restrict__ dl, int n, const int* __restrict__ flagp,
    int use_flag) {
  int bf = use_flag ? flagp[0] : 0;
  int i0 = (blockIdx.x * 256 + threadIdx.x) * 4;
  if (i0 >= n) return;
#pragma unroll
  for (int j = 0; j < 4; j++) {
    float f = gload(src, i0 + j, bf);
    __hip_bfloat16 h = __float2bfloat16(f);
    dh[i0 + j] = h;
    dl[i0 + j] = __float2bfloat16(f - __bfloat162float(h));
  }
}

// Transpose + split: src flagged [R, C] -> dh/dl bf16 [C, R]. 64x64 LDS tiles.
__global__ __launch_bounds__(256) void tsplit(
    const void* __restrict__ src, __hip_bfloat16* __restrict__ dh,
    __hip_bfloat16* __restrict__ dl, int R, int C,
    const int* __restrict__ flagp) {
  int bf = flagp[0];
  __shared__ float t[64][65];
  int r0 = blockIdx.y * 64, c0 = blockIdx.x * 64;
  int cl = threadIdx.x & 63, rl = threadIdx.x >> 6;
#pragma unroll
  for (int i = 0; i < 16; i++) {
    int rr = rl + i * 4;
    t[rr][cl] = gload(src, (long)(r0 + rr) * C + c0 + cl, bf);
  }
  __syncthreads();
#pragma unroll
  for (int i = 0; i < 16; i++) {
    int cc = rl + i * 4;
    float f = t[cl][cc];  // lanes vary cl -> stride 65 -> conflict-free
    __hip_bfloat16 h = __float2bfloat16(f);
    long o = (long)(c0 + cc) * R + r0 + cl;
    dh[o] = h;
    dl[o] = __float2bfloat16(f - __bfloat162float(h));
  }
}

// Batched transpose+split for values: src fp32 [Z][256, 64] -> dh/dl [Z][64, 256].
__global__ __launch_bounds__(256) void vtsplit(
    const float* __restrict__ src, __hip_bfloat16* __restrict__ dh,
    __hip_bfloat16* __restrict__ dl) {
  __shared__ float tle[64][65];
  const int z = blockIdx.y;        // 96 = B*H
  const int r0 = blockIdx.x * 64;  // 4 row-tiles over n=256
  const float* s = src + (long)z * 16384;
  int cl = threadIdx.x & 63, rl4 = threadIdx.x >> 6;
#pragma unroll
  for (int i = 0; i < 16; i++) {
    int rr = rl4 + i * 4;
    tle[rr][cl] = s[(r0 + rr) * 64 + cl];
  }
  __syncthreads();
#pragma unroll
  for (int i = 0; i < 16; i++) {
    int cc = rl4 + i * 4;          // d index
    float f = tle[cl][cc];         // = src[n=r0+cl][d=cc]
    __hip_bfloat16 h = __float2bfloat16(f);
    long o = (long)z * 16384 + (long)cc * 256 + r0 + cl;
    dh[o] = h;
    dl[o] = __float2bfloat16(f - __bfloat162float(h));
  }
}

// ---------------------------------------------------------------------------
// LDS-staged MFMA NT GEMM (m97 structure), split-bf16 3-pass folded into the
// K loop: pass 0 = Ah*Bh, pass 1 = Ah*Bl, pass 2 = Al*Bh.
// pmask_bf: bitmask of passes to run when flag==1 (bf16 inputs -> some lo
// buffers are exactly zero, so their passes are skipped losslessly).
// Block = 4 waves (2x2), tile 128x128, wave tile 64x64 (4x4 frags), BK=32.
// ---------------------------------------------------------------------------
__device__ __forceinline__ void stage_tile(
    const __hip_bfloat16* __restrict__ src, int ld, __hip_bfloat16* lds, int t) {
  int row = t >> 2;
  int col = (t & 3) * 8;
  int wavebase = (t >> 6) * 1024;  // bytes
#pragma unroll
  for (int i = 0; i < 2; i++) {
    const __hip_bfloat16* gp = src + (long)(i * 64 + row) * ld + col;
    __builtin_amdgcn_global_load_lds(
        (const __attribute__((address_space(1))) void*)gp,
        (__attribute__((address_space(3))) void*)((char*)lds + i * 4096 + wavebase),
        16, 0, 0);
  }
}

__global__ __launch_bounds__(256) void mfma_nt_lds(
    const __hip_bfloat16* __restrict__ Ah_g, const __hip_bfloat16* __restrict__ Al_g,
    const __hip_bfloat16* __restrict__ Wh_g, const __hip_bfloat16* __restrict__ Wl_g,
    void* __restrict__ Cout, int K, int lda, int ldb, long a_batch, long c_batch,
    int om, int oh, const int* __restrict__ flagp, int use_flag, int pmask_bf) {
  int flag = flagp[0];
  int bf = use_flag ? flag : 0;
  __shared__ __hip_bfloat16 As[128 * 32];
  __shared__ __hip_bfloat16 Bs[128 * 32];

  // Bijective XCD-aware swizzle over the flattened grid (nwg % 8 == 0 here).
  const int gx = gridDim.x, gy = gridDim.y;
  const int nwg = gx * gy * gridDim.z;
  const int lin = (blockIdx.z * gy + blockIdx.y) * gx + blockIdx.x;
  const int swz = (lin & 7) * (nwg >> 3) + (lin >> 3);
  const int bx = swz % gx;
  const int rem = swz / gx;
  const int by = rem % gy;
  const int bz = rem / gy;

  const int m0 = by * 128, n0 = bx * 128;
  const int t = threadIdx.x;
  const int lane = t & 63;
  const int r = lane & 15, g = lane >> 4;
  const int wave = t >> 6;
  const int wm = (wave >> 1) * 64, wn = (wave & 1) * 64;

  const __hip_bfloat16* Abh = Ah_g + (long)bz * a_batch;
  const __hip_bfloat16* Abl = Al_g + (long)bz * a_batch;

  f32x4 zero4 = {0.f, 0.f, 0.f, 0.f};
  f32x4 acc[4][4];
#pragma unroll
  for (int fi = 0; fi < 4; fi++)
#pragma unroll
    for (int fj = 0; fj < 4; fj++) acc[fi][fj] = zero4;

  for (int pass = 0; pass < 3; pass++) {
    if (flag && !((pmask_bf >> pass) & 1)) continue;
    const __hip_bfloat16* Ab = (pass < 2) ? Abh : Abl;
    const __hip_bfloat16* Bb = (pass == 1) ? Wl_g : Wh_g;
    const __hip_bfloat16* Arow = Ab + (long)m0 * lda;
    const __hip_bfloat16* Brow = Bb + (long)n0 * ldb;
    for (int k0 = 0; k0 < K; k0 += 32) {
      stage_tile(Arow + k0, lda, As, t);
      stage_tile(Brow + k0, ldb, Bs, t);
      __syncthreads();  // drains vmcnt(0) before barrier (compiler-enforced)
      bf16x8 af[4], bw[4];
#pragma unroll
      for (int fi = 0; fi < 4; fi++)
        af[fi] = *(const bf16x8*)(As + (wm + fi * 16 + r) * 32 + g * 8);
#pragma unroll
      for (int fj = 0; fj < 4; fj++)
        bw[fj] = *(const bf16x8*)(Bs + (wn + fj * 16 + r) * 32 + g * 8);
#pragma unroll
      for (int fi = 0; fi < 4; fi++)
#pragma unroll
        for (int fj = 0; fj < 4; fj++)
          acc[fi][fj] = __builtin_amdgcn_mfma_f32_16x16x32_bf16(
              af[fi], bw[fj], acc[fi][fj], 0, 0, 0);
      __syncthreads();  // protect LDS before next stage overwrites
    }
  }

#pragma unroll
  for (int fi = 0; fi < 4; fi++)
#pragma unroll
    for (int fj = 0; fj < 4; fj++)
#pragma unroll
      for (int v = 0; v < 4; v++) {
        int m = m0 + wm + fi * 16 + g * 4 + v;  // row = (lane>>4)*4 + reg
        int n = n0 + wn + fj * 16 + r;          // col = lane&15
        long off = (long)bz * c_batch + (long)m * om + (long)(n >> 6) * oh + (n & 63);
        float val = acc[fi][fj][v];
        if (bf) ((__hip_bfloat16*)Cout)[off] = __float2bfloat16(val);
        else    ((float*)Cout)[off] = val;
      }
}

// ---------------------------------------------------------------------------
// bmu[b,d] = sum_n w_mu[n] * Bmat[n, b*768+d]   (and bsig with w_sigma)
// ---------------------------------------------------------------------------
__global__ __launch_bounds__(256) void bvec(
    const float* __restrict__ Bmat, const float* __restrict__ wmuf,
    const float* __restrict__ wsigf, float* __restrict__ bmu,
    float* __restrict__ bsig) {
  int t = blockIdx.x * 256 + threadIdx.x;
  int w = t / 6144, r = t % 6144;
  const float* wv = w ? wsigf : wmuf;
  float acc = 0.f;
  for (int n = 0; n < NB; n++) acc += wv[n] * Bmat[(long)n * 6144 + r];
  (w ? bsig : bmu)[r] = acc;
}

// kmu[b,c] = sum_d bmu[b,d] * Wk[c,d]   (c = h*64+dh), and ksig with bsig.
__global__ __launch_bounds__(256) void kvec(
    const float* __restrict__ Wkf, const float* __restrict__ bmu,
    const float* __restrict__ bsig, float* __restrict__ kmu,
    float* __restrict__ ksig) {
  int t = blockIdx.x * 256 + threadIdx.x;
  int w = t / 6144, r = t % 6144;
  int b = r / 768, c = r % 768;
  const float* bv = (w ? bsig : bmu) + b * 768;
  const float* wk = Wkf + (long)c * 768;
  float acc = 0.f;
  for (int d = 0; d < 768; d++) acc += bv[d] * wk[d];
  (w ? ksig : kmu)[r] = acc;
}

// wqm[b,h,d] = sum_dh Wq[h*64+dh, d] * kmu[b, h*64+dh]   (and wqs with ksig)
__global__ __launch_bounds__(256) void wqvec(
    const float* __restrict__ Wqf, const float* __restrict__ kmu,
    const float* __restrict__ ksig, float* __restrict__ wqm,
    float* __restrict__ wqs) {
  int t = blockIdx.x * 256 + threadIdx.x;
  int w = t / 73728, r = t % 73728;
  int b = r / 9216, h = (r % 9216) / 768, d = r % 768;
  const float* kv = (w ? ksig : kmu) + b * 768 + h * 64;
  float acc = 0.f;
  for (int dh = 0; dh < 64; dh++)
    acc += Wqf[(long)(h * 64 + dh) * 768 + d] * kv[dh];
  (w ? wqs : wqm)[r] = acc;
}

// ---------------------------------------------------------------------------
// amu[b, hh, qrow] = dot768(q[qrow, b, :], wq{m|s}[b, hh, :]); one wave/q-row.
// ---------------------------------------------------------------------------
__global__ __launch_bounds__(256) void amu_kernel(
    const void* __restrict__ q, const float* __restrict__ wqm,
    const float* __restrict__ wqs, float* __restrict__ amu,
    const int* __restrict__ flagp) {
  int bf = flagp[0];
  int lane = threadIdx.x & 63;
  int wave = threadIdx.x >> 6;
  int qrow = blockIdx.x * 4 + wave;
  int b = blockIdx.y;
  float qv[12];
  long base = ((long)qrow * 8 + b) * 768 + lane;
#pragma unroll
  for (int j = 0; j < 12; j++) qv[j] = gload(q, base + 64 * j, bf);
  for (int hh = 0; hh < 24; hh++) {
    const float* vec = (hh < 12) ? (wqm + ((long)b * 12 + hh) * 768)
                                 : (wqs + ((long)b * 12 + hh - 12) * 768);
    float p = 0.f;
#pragma unroll
    for (int j = 0; j < 12; j++) p += qv[j] * vec[lane + 64 * j];
#pragma unroll
    for (int m = 32; m >= 1; m >>= 1) p += __shfl_xor(p, m);
    if (lane == 0) amu[((long)b * 24 + hh) * 1024 + qrow] = p;
  }
}

// ---------------------------------------------------------------------------
// Fused MFMA attention: ctx[q,d] = sum_n r(q,n) * V[n,d] per (b,h).
// A = R computed in-register (split rh/rl), B = V^T (pre-split bf16 h/l).
// Wave tile: 32 q (fi=0,1) x 64 d (fj=0..3), K = 256 n in 8 k-steps.
// 3 MFMA passes: rh*vh + rl*vh + rh*vl (rl*vl ~ 2^-34, dropped).
// Writes ctx directly as split-bf16 for the final MFMA GEMM.
// ---------------------------------------------------------------------------
__global__ __launch_bounds__(256) void attn_mfma(
    const __hip_bfloat16* __restrict__ Vth, const __hip_bfloat16* __restrict__ Vtl,
    const float* __restrict__ amu, const float* __restrict__ mubf,
    const float* __restrict__ sigbf, __hip_bfloat16* __restrict__ Ch,
    __hip_bfloat16* __restrict__ Cl) {
  const int qch = blockIdx.x, h = blockIdx.y, b = blockIdx.z;
  const int t = threadIdx.x;
  const int lane = t & 63, wave = t >> 6;
  const int r = lane & 15, g = lane >> 4;
  const int wq = wave * 32;
  __shared__ float s_mub[NB], s_sb2[NB];
  {
    float sb = sigbf[t];
    s_mub[t] = mubf[t];
    s_sb2[t] = sb * sb;
  }
  __syncthreads();

  // per-lane (mu, sig) for its two A-fragment rows: q = qch*128 + wq + fi*16 + r
  float mu_[2], sig_[2];
#pragma unroll
  for (int fi = 0; fi < 2; fi++) {
    int q = qch * 128 + wq + fi * 16 + r;
    float araw = amu[((long)b * 24 + h) * 1024 + q] * 0.125f;
    float sraw = amu[((long)b * 24 + 12 + h) * 1024 + q] * 0.125f;
    mu_[fi] = 1.f / (1.f + expf(-araw));
    sig_[fi] = fmaxf(sraw, 0.f) + log1pf(expf(-fabsf(sraw)));  // softplus
  }

  const __hip_bfloat16* vhb = Vth + ((long)b * 12 + h) * 16384;
  const __hip_bfloat16* vlb = Vtl + ((long)b * 12 + h) * 16384;

  f32x4 zero4 = {0.f, 0.f, 0.f, 0.f};
  f32x4 acc[2][4];
#pragma unroll
  for (int fi = 0; fi < 2; fi++)
#pragma unroll
    for (int fj = 0; fj < 4; fj++) acc[fi][fj] = zero4;

  for (int ks = 0; ks < 8; ks++) {
    // Build A fragments: r-values for n = ks*32 + g*8 + j (same k-map as B).
    bf16x8 rh[2], rl[2];
#pragma unroll
    for (int fi = 0; fi < 2; fi++) {
      float mu = mu_[fi], sg = sig_[fi];
#pragma unroll
      for (int j = 0; j < 8; j++) {
        int n = ks * 32 + g * 8 + j;
        float inv_s = rsqrtf(s_sb2[n] + sg);
        float tt = (mu - s_mub[n]) * inv_s;
        float rv = 0.3989422804014327f * inv_s *
                   exp2f(-0.7213475204444817f * tt * tt);
        __bf16 hi = (__bf16)rv;
        rh[fi][j] = hi;
        rl[fi][j] = (__bf16)(rv - (float)hi);  // split exact by construction
      }
    }
#pragma unroll
    for (int fj = 0; fj < 4; fj++) {
      long vo = (long)(fj * 16 + r) * 256 + ks * 32 + g * 8;
      bf16x8 vh = *(const bf16x8*)(vhb + vo);
      bf16x8 vl = *(const bf16x8*)(vlb + vo);
#pragma unroll
      for (int fi = 0; fi < 2; fi++) {
        acc[fi][fj] = __builtin_amdgcn_mfma_f32_16x16x32_bf16(
            rh[fi], vh, acc[fi][fj], 0, 0, 0);
        acc[fi][fj] = __builtin_amdgcn_mfma_f32_16x16x32_bf16(
            rl[fi], vh, acc[fi][fj], 0, 0, 0);
        acc[fi][fj] = __builtin_amdgcn_mfma_f32_16x16x32_bf16(
            rh[fi], vl, acc[fi][fj], 0, 0, 0);
      }
    }
  }

#pragma unroll
  for (int fi = 0; fi < 2; fi++)
#pragma unroll
    for (int fj = 0; fj < 4; fj++)
#pragma unroll
      for (int v = 0; v < 4; v++) {
        int q = qch * 128 + wq + fi * 16 + g * 4 + v;  // row = (lane>>4)*4+reg
        int d = fj * 16 + r;                            // col = lane&15
        long off = ((long)(b * SLEN + q)) * DM + h * HEAD + d;
        float f = acc[fi][fj][v];
        __hip_bfloat16 hh = __float2bfloat16(f);
        Ch[off] = hh;
        Cl[off] = __float2bfloat16(f - __bfloat162float(hh));
      }
}

// ---------------------------------------------------------------------------
extern "C" void kernel_launch(void* const* d_in, const int* in_sizes, int n_in,
                              void* d_out, int out_size, void* d_ws, size_t ws_size,
                              hipStream_t stream) {
  const void* x    = d_in[0];
  const void* q    = d_in[1];
  const void* Wq   = d_in[2];
  const void* Wk   = d_in[3];
  const void* Wv   = d_in[4];
  const void* Wo   = d_in[5];
  const void* wmu  = d_in[6];
  const void* wsig = d_in[7];
  const void* mub  = d_in[8];
  const void* sigb = d_in[9];
  const void* G    = d_in[10];

  int* flagp = (int*)d_ws;
  float* base = (float*)d_ws + 16;
  float* Wqf   = base;              // 589824
  float* Wkf   = Wqf + 589824;      // 589824
  float* wmuf  = Wkf + 589824;      // 256
  float* wsigf = wmuf + 256;        // 256
  float* mubf  = wsigf + 256;       // 256
  float* sigbf = mubf + 256;        // 256
  float* Bmat  = sigbf + 256;       // 1572864  [256, 6144] fp32
  float* values= Bmat + 1572864;    // 1572864  [B,H,256,64] fp32
  float* bmu   = values + 1572864;  // 6144
  float* bsig  = bmu + 6144;        // 6144
  float* kmu   = bsig + 6144;       // 6144
  float* ksig  = kmu + 6144;        // 6144
  float* wqm   = ksig + 6144;       // 73728
  float* wqs   = wqm + 73728;       // 73728
  float* amu   = wqs + 73728;       // 196608  [B,24,1024]
  // bf16 arrays (element counts; all 16B-aligned)
  __hip_bfloat16* Wvh = (__hip_bfloat16*)(amu + 196608);  // 589824
  __hip_bfloat16* Wvl = Wvh + 589824;   // 589824
  __hip_bfloat16* Woh = Wvl + 589824;   // 589824
  __hip_bfloat16* Wol = Woh + 589824;   // 589824
  __hip_bfloat16* Gth = Wol + 589824;   // 262144  [256,1024]
  __hip_bfloat16* Gtl = Gth + 262144;   // 262144
  __hip_bfloat16* Bh  = Gtl + 262144;   // 1572864 [256,6144]
  __hip_bfloat16* Bl  = Bh + 1572864;   // 1572864
  // XCh/XCl: holds x^T [6144,1024] for GEMM1, then reused as ctx-split
  // [8192,768] for GEMM3 (GEMM1 strictly precedes attn on the stream).
  __hip_bfloat16* XCh = Bl + 1572864;   // 6291456
  __hip_bfloat16* XCl = XCh + 6291456;  // 6291456
  __hip_bfloat16* Vth = XCl + 6291456;  // 1572864 [B,H,64,256] split V^T
  __hip_bfloat16* Vtl = Vth + 1572864;  // 1572864
  // total ~63 MB

  detect_dtype<<<1, 256, 0, stream>>>(x, flagp);

  // fp32 copies needed by the collapse chain
  convertk<<<2304, 256, 0, stream>>>(Wq, Wqf, 589824, flagp);
  convertk<<<2304, 256, 0, stream>>>(Wk, Wkf, 589824, flagp);
  convertk<<<1, 256, 0, stream>>>(wmu, wmuf, 256, flagp);
  convertk<<<1, 256, 0, stream>>>(wsig, wsigf, 256, flagp);
  convertk<<<1, 256, 0, stream>>>(mub, mubf, 256, flagp);
  convertk<<<1, 256, 0, stream>>>(sigb, sigbf, 256, flagp);

  // bf16-split operands for the MFMA GEMMs
  tsplit<<<dim3(4, 16), 256, 0, stream>>>(G, Gth, Gtl, 1024, 256, flagp);
  tsplit<<<dim3(96, 16), 256, 0, stream>>>(x, XCh, XCl, 1024, 6144, flagp);
  split4<<<576, 256, 0, stream>>>(Wv, Wvh, Wvl, 589824, flagp, 1);
  split4<<<576, 256, 0, stream>>>(Wo, Woh, Wol, 589824, flagp, 1);

  // GEMM1: Bmat[m,n] = sum_k Gt[m,k] * Xt[n,k]; M=256 N=6144 K=1024 -> fp32
  // bf16 inputs: pass 0 only (lossless — both lo buffers are exactly zero).
  mfma_nt_lds<<<dim3(48, 2, 1), 256, 0, stream>>>(
      Gth, Gtl, XCh, XCl, Bmat, /*K=*/1024, /*lda=*/1024, /*ldb=*/1024,
      /*a_batch=*/0, /*c_batch=*/0, /*om=*/6144, /*oh=*/64, flagp, 0, /*pmask_bf=*/1);

  split4<<<1536, 256, 0, stream>>>(Bmat, Bh, Bl, 1572864, flagp, 0);

  // GEMM2: values(z) = Bmat_z @ Wv^T -> [B,H,256,64] fp32 (bf16: skip Ah*Wl)
  mfma_nt_lds<<<dim3(6, 2, 8), 256, 0, stream>>>(
      Bh, Bl, Wvh, Wvl, values, /*K=*/768, /*lda=*/6144, /*ldb=*/768,
      /*a_batch=*/768, /*c_batch=*/196608, /*om=*/64, /*oh=*/16384, flagp, 0,
      /*pmask_bf=*/5);

  // V^T split for MFMA attention
  vtsplit<<<dim3(4, 96), 256, 0, stream>>>(values, Vth, Vtl);

  // scores@w collapse chain: bmu/bsig -> kmu/ksig -> wqm/wqs -> amu
  bvec<<<48, 256, 0, stream>>>(Bmat, wmuf, wsigf, bmu, bsig);
  kvec<<<48, 256, 0, stream>>>(Wkf, bmu, bsig, kmu, ksig);
  wqvec<<<576, 256, 0, stream>>>(Wqf, kmu, ksig, wqm, wqs);
  amu_kernel<<<dim3(256, 8), 256, 0, stream>>>(q, wqm, wqs, amu, flagp);

  // fused MFMA attention -> ctx split-bf16 [8192,768] (into XCh/XCl)
  attn_mfma<<<dim3(8, 12, 8), 256, 0, stream>>>(
      Vth, Vtl, amu, mubf, sigbf, XCh, XCl);

  // GEMM3: out = ctx @ Wo^T; M=8192 N=768 K=768 (bf16: skip Ah*Wl pass)
  mfma_nt_lds<<<dim3(6, 64, 1), 256, 0, stream>>>(
      XCh, XCl, Woh, Wol, d_out, /*K=*/768, /*lda=*/768, /*ldb=*/768,
      /*a_batch=*/0, /*c_batch=*/0, /*om=*/768, /*oh=*/64, flagp, 1,
      /*pmask_bf=*/5);
}

// Round 4
// 423.122 us; speedup vs baseline: 1.2501x; 1.0252x over previous
//
#include <hip/hip_runtime.h>
#include <hip/hip_bf16.h>
#include <math.h>

#define NHEADS 12
#define HEAD   64
#define DM     768
#define NB     256
#define SLEN   1024
#define NBATCH 8

typedef __bf16 bf16x8 __attribute__((ext_vector_type(8)));
typedef float  f32x4  __attribute__((ext_vector_type(4)));

// Flag semantics: 1 = inputs are bf16, 0 = inputs are fp32.
__device__ __forceinline__ float gload(const void* p, long i, int bf) {
  return bf ? __bfloat162float(((const __hip_bfloat16*)p)[i])
            : ((const float*)p)[i];
}

// ---------------------------------------------------------------------------
// Detect input dtype. If the buffer holds bf16 N(0,1) data, max|bf16| ~ 4.
// If it holds fp32 data, the interleaved low-mantissa halves read as bf16 have
// uniform-random exponents -> max is astronomically large (w.p. 1 - 1e-60).
// ---------------------------------------------------------------------------
__global__ void detect_dtype(const void* x, int* flag) {
  __shared__ float red[256];
  int t = threadIdx.x;
  const __hip_bfloat16* p = (const __hip_bfloat16*)x;
  float a = fabsf(__bfloat162float(p[t * 2]));
  float b = fabsf(__bfloat162float(p[t * 2 + 1]));
  float m = fmaxf(a, b);
  red[t] = m;
  __syncthreads();
  for (int s = 128; s > 0; s >>= 1) {
    if (t < s) red[t] = fmaxf(red[t], red[t + s]);
    __syncthreads();
  }
  if (t == 0) flag[0] = (red[0] < 1e4f) ? 1 : 0;
}

// Convert any input tensor to a canonical fp32 workspace copy.
__global__ void convertk(const void* __restrict__ src, float* __restrict__ dst,
                         int n, const int* __restrict__ flagp) {
  int bf = flagp[0];
  int i = blockIdx.x * 256 + threadIdx.x;
  if (i < n) dst[i] = gload(src, i, bf);
}

// Zero-fill fp32 buffer (n multiple of 4).
__global__ __launch_bounds__(256) void zerok(float* __restrict__ p, long n) {
  long i = ((long)blockIdx.x * 256 + threadIdx.x) * 4;
  if (i < n) {
    f32x4 z = {0.f, 0.f, 0.f, 0.f};
    *(f32x4*)(p + i) = z;
  }
}

// ---------------------------------------------------------------------------
// Split-bf16 precision scheme: a = ah + al with ah = bf16(a), al = bf16(a-ah).
// a*b ~ ah*bh + ah*bl + al*bh, dropped al*bl term <= 2^-16 relative.
// ---------------------------------------------------------------------------
__global__ __launch_bounds__(256) void split4(
    const void* __restrict__ src, __hip_bfloat16* __restrict__ dh,
    __hip_bfloat16* __restrict__ dl, int n, const int* __restrict__ flagp,
    int use_flag) {
  int bf = use_flag ? flagp[0] : 0;
  int i0 = (blockIdx.x * 256 + threadIdx.x) * 4;
  if (i0 >= n) return;
#pragma unroll
  for (int j = 0; j < 4; j++) {
    float f = gload(src, i0 + j, bf);
    __hip_bfloat16 h = __float2bfloat16(f);
    dh[i0 + j] = h;
    dl[i0 + j] = __float2bfloat16(f - __bfloat162float(h));
  }
}

// Transpose + split: src flagged [R, C] -> dh/dl bf16 [C, R]. 64x64 LDS tiles.
__global__ __launch_bounds__(256) void tsplit(
    const void* __restrict__ src, __hip_bfloat16* __restrict__ dh,
    __hip_bfloat16* __restrict__ dl, int R, int C,
    const int* __restrict__ flagp) {
  int bf = flagp[0];
  __shared__ float t[64][65];
  int r0 = blockIdx.y * 64, c0 = blockIdx.x * 64;
  int cl = threadIdx.x & 63, rl = threadIdx.x >> 6;
#pragma unroll
  for (int i = 0; i < 16; i++) {
    int rr = rl + i * 4;
    t[rr][cl] = gload(src, (long)(r0 + rr) * C + c0 + cl, bf);
  }
  __syncthreads();
#pragma unroll
  for (int i = 0; i < 16; i++) {
    int cc = rl + i * 4;
    float f = t[cl][cc];  // lanes vary cl -> stride 65 -> conflict-free
    __hip_bfloat16 h = __float2bfloat16(f);
    long o = (long)(c0 + cc) * R + r0 + cl;
    dh[o] = h;
    dl[o] = __float2bfloat16(f - __bfloat162float(h));
  }
}

// Batched transpose+split for values: src fp32 [Z][256, 64] -> dh/dl [Z][64, 256].
__global__ __launch_bounds__(256) void vtsplit(
    const float* __restrict__ src, __hip_bfloat16* __restrict__ dh,
    __hip_bfloat16* __restrict__ dl) {
  __shared__ float tle[64][65];
  const int z = blockIdx.y;        // 96 = B*H
  const int r0 = blockIdx.x * 64;  // 4 row-tiles over n=256
  const float* s = src + (long)z * 16384;
  int cl = threadIdx.x & 63, rl4 = threadIdx.x >> 6;
#pragma unroll
  for (int i = 0; i < 16; i++) {
    int rr = rl4 + i * 4;
    tle[rr][cl] = s[(r0 + rr) * 64 + cl];
  }
  __syncthreads();
#pragma unroll
  for (int i = 0; i < 16; i++) {
    int cc = rl4 + i * 4;          // d index
    float f = tle[cl][cc];         // = src[n=r0+cl][d=cc]
    __hip_bfloat16 h = __float2bfloat16(f);
    long o = (long)z * 16384 + (long)cc * 256 + r0 + cl;
    dh[o] = h;
    dl[o] = __float2bfloat16(f - __bfloat162float(h));
  }
}

// ---------------------------------------------------------------------------
// LDS-staged MFMA NT GEMM, double-buffered (single barrier per K-iter),
// split-bf16 passes: 0 = Ah*Bh, 1 = Ah*Bl, 2 = Al*Bh.
// pmask_bf: passes to run when flag==1 (zero lo-buffers skipped losslessly).
// ksplit: K split across gridDim.z (z = batch*ksplit); when ksplit>1 the
// epilogue atomicAdds fp32 partials into a zero-initialized Cout.
// Block = 4 waves (2x2), tile 128x128, wave tile 64x64 (4x4 frags), BK=32.
// C/D mapping: col=lane&15, row=(lane>>4)*4+reg (HW-verified).
// ---------------------------------------------------------------------------
__device__ __forceinline__ void stage_tile(
    const __hip_bfloat16* __restrict__ src, int ld, __hip_bfloat16* lds, int t) {
  int row = t >> 2;
  int col = (t & 3) * 8;
  int wavebase = (t >> 6) * 1024;  // bytes
#pragma unroll
  for (int i = 0; i < 2; i++) {
    const __hip_bfloat16* gp = src + (long)(i * 64 + row) * ld + col;
    __builtin_amdgcn_global_load_lds(
        (const __attribute__((address_space(1))) void*)gp,
        (__attribute__((address_space(3))) void*)((char*)lds + i * 4096 + wavebase),
        16, 0, 0);
  }
}

__global__ __launch_bounds__(256) void mfma_nt_lds(
    const __hip_bfloat16* __restrict__ Ah_g, const __hip_bfloat16* __restrict__ Al_g,
    const __hip_bfloat16* __restrict__ Wh_g, const __hip_bfloat16* __restrict__ Wl_g,
    void* __restrict__ Cout, int K, int lda, int ldb, long a_batch, long c_batch,
    int om, int oh, const int* __restrict__ flagp, int use_flag, int pmask_bf,
    int ksplit) {
  int flag = flagp[0];
  int bf = use_flag ? flag : 0;
  __shared__ __hip_bfloat16 As0[4096], As1[4096];
  __shared__ __hip_bfloat16 Bs0[4096], Bs1[4096];

  // Bijective XCD-aware swizzle over the flattened grid (nwg % 8 == 0 here).
  const int gx = gridDim.x, gy = gridDim.y;
  const int nwg = gx * gy * gridDim.z;
  const int lin = (blockIdx.z * gy + blockIdx.y) * gx + blockIdx.x;
  const int swz = (lin & 7) * (nwg >> 3) + (lin >> 3);
  const int bx = swz % gx;
  const int rem = swz / gx;
  const int by = rem % gy;
  const int bzf = rem / gy;
  const int bz = bzf / ksplit;          // batch index
  const int kc = bzf - bz * ksplit;     // K-chunk index
  const int Ks = K / ksplit;
  const int kbeg = kc * Ks, kend = kbeg + Ks;

  const int m0 = by * 128, n0 = bx * 128;
  const int t = threadIdx.x;
  const int lane = t & 63;
  const int r = lane & 15, g = lane >> 4;
  const int wave = t >> 6;
  const int wm = (wave >> 1) * 64, wn = (wave & 1) * 64;

  const __hip_bfloat16* Abh = Ah_g + (long)bz * a_batch;
  const __hip_bfloat16* Abl = Al_g + (long)bz * a_batch;

  f32x4 zero4 = {0.f, 0.f, 0.f, 0.f};
  f32x4 acc[4][4];
#pragma unroll
  for (int fi = 0; fi < 4; fi++)
#pragma unroll
    for (int fj = 0; fj < 4; fj++) acc[fi][fj] = zero4;

  for (int pass = 0; pass < 3; pass++) {
    if (flag && !((pmask_bf >> pass) & 1)) continue;
    const __hip_bfloat16* Arow = ((pass < 2) ? Abh : Abl) + (long)m0 * lda;
    const __hip_bfloat16* Brow = ((pass == 1) ? Wl_g : Wh_g) + (long)n0 * ldb;
    // Prologue: stage first tile of this pass into buffer 0.
    stage_tile(Arow + kbeg, lda, As0, t);
    stage_tile(Brow + kbeg, ldb, Bs0, t);
    __syncthreads();
    int cur = 0;
    for (int k0 = kbeg; k0 < kend; k0 += 32) {
      const __hip_bfloat16* Asc = cur ? As1 : As0;
      const __hip_bfloat16* Bsc = cur ? Bs1 : Bs0;
      bf16x8 af[4], bw[4];
#pragma unroll
      for (int fi = 0; fi < 4; fi++)
        af[fi] = *(const bf16x8*)(Asc + (wm + fi * 16 + r) * 32 + g * 8);
#pragma unroll
      for (int fj = 0; fj < 4; fj++)
        bw[fj] = *(const bf16x8*)(Bsc + (wn + fj * 16 + r) * 32 + g * 8);
      // Prefetch next tile into the other buffer; its loads progress under
      // the MFMA below, so the barrier drain pays only residual latency.
      if (k0 + 32 < kend) {
        stage_tile(Arow + k0 + 32, lda, cur ? As0 : As1, t);
        stage_tile(Brow + k0 + 32, ldb, cur ? Bs0 : Bs1, t);
      }
#pragma unroll
      for (int fi = 0; fi < 4; fi++)
#pragma unroll
        for (int fj = 0; fj < 4; fj++)
          acc[fi][fj] = __builtin_amdgcn_mfma_f32_16x16x32_bf16(
              af[fi], bw[fj], acc[fi][fj], 0, 0, 0);
      __syncthreads();  // drains prefetch + protects LDS buffer reuse
      cur ^= 1;
    }
  }

  if (ksplit > 1) {
    float* Cf = (float*)Cout;
#pragma unroll
    for (int fi = 0; fi < 4; fi++)
#pragma unroll
      for (int fj = 0; fj < 4; fj++)
#pragma unroll
        for (int v = 0; v < 4; v++) {
          int m = m0 + wm + fi * 16 + g * 4 + v;
          int n = n0 + wn + fj * 16 + r;
          long off = (long)bz * c_batch + (long)m * om + (long)(n >> 6) * oh + (n & 63);
          atomicAdd(Cf + off, acc[fi][fj][v]);
        }
  } else {
#pragma unroll
    for (int fi = 0; fi < 4; fi++)
#pragma unroll
      for (int fj = 0; fj < 4; fj++)
#pragma unroll
        for (int v = 0; v < 4; v++) {
          int m = m0 + wm + fi * 16 + g * 4 + v;  // row = (lane>>4)*4 + reg
          int n = n0 + wn + fj * 16 + r;          // col = lane&15
          long off = (long)bz * c_batch + (long)m * om + (long)(n >> 6) * oh + (n & 63);
          float val = acc[fi][fj][v];
          if (bf) ((__hip_bfloat16*)Cout)[off] = __float2bfloat16(val);
          else    ((float*)Cout)[off] = val;
        }
  }
}

// ---------------------------------------------------------------------------
// bmu[b,d] = sum_n w_mu[n] * Bmat[n, b*768+d]   (and bsig with w_sigma)
// ---------------------------------------------------------------------------
__global__ __launch_bounds__(256) void bvec(
    const float* __restrict__ Bmat, const float* __restrict__ wmuf,
    const float* __restrict__ wsigf, float* __restrict__ bmu,
    float* __restrict__ bsig) {
  int t = blockIdx.x * 256 + threadIdx.x;
  int w = t / 6144, r = t % 6144;
  const float* wv = w ? wsigf : wmuf;
  float acc = 0.f;
  for (int n = 0; n < NB; n++) acc += wv[n] * Bmat[(long)n * 6144 + r];
  (w ? bsig : bmu)[r] = acc;
}

// kmu[b,c] = sum_d bmu[b,d] * Wk[c,d]   (c = h*64+dh), and ksig with bsig.
__global__ __launch_bounds__(256) void kvec(
    const float* __restrict__ Wkf, const float* __restrict__ bmu,
    const float* __restrict__ bsig, float* __restrict__ kmu,
    float* __restrict__ ksig) {
  int t = blockIdx.x * 256 + threadIdx.x;
  int w = t / 6144, r = t % 6144;
  int b = r / 768, c = r % 768;
  const float* bv = (w ? bsig : bmu) + b * 768;
  const float* wk = Wkf + (long)c * 768;
  float acc = 0.f;
  for (int d = 0; d < 768; d++) acc += bv[d] * wk[d];
  (w ? ksig : kmu)[r] = acc;
}

// wqm[b,h,d] = sum_dh Wq[h*64+dh, d] * kmu[b, h*64+dh]   (and wqs with ksig)
__global__ __launch_bounds__(256) void wqvec(
    const float* __restrict__ Wqf, const float* __restrict__ kmu,
    const float* __restrict__ ksig, float* __restrict__ wqm,
    float* __restrict__ wqs) {
  int t = blockIdx.x * 256 + threadIdx.x;
  int w = t / 73728, r = t % 73728;
  int b = r / 9216, h = (r % 9216) / 768, d = r % 768;
  const float* kv = (w ? ksig : kmu) + b * 768 + h * 64;
  float acc = 0.f;
  for (int dh = 0; dh < 64; dh++)
    acc += Wqf[(long)(h * 64 + dh) * 768 + d] * kv[dh];
  (w ? wqs : wqm)[r] = acc;
}

// ---------------------------------------------------------------------------
// amu[b, hh, qrow] = dot768(q[qrow, b, :], wq{m|s}[b, hh, :]); one wave/q-row.
// ---------------------------------------------------------------------------
__global__ __launch_bounds__(256) void amu_kernel(
    const void* __restrict__ q, const float* __restrict__ wqm,
    const float* __restrict__ wqs, float* __restrict__ amu,
    const int* __restrict__ flagp) {
  int bf = flagp[0];
  int lane = threadIdx.x & 63;
  int wave = threadIdx.x >> 6;
  int qrow = blockIdx.x * 4 + wave;
  int b = blockIdx.y;
  float qv[12];
  long base = ((long)qrow * 8 + b) * 768 + lane;
#pragma unroll
  for (int j = 0; j < 12; j++) qv[j] = gload(q, base + 64 * j, bf);
  for (int hh = 0; hh < 24; hh++) {
    const float* vec = (hh < 12) ? (wqm + ((long)b * 12 + hh) * 768)
                                 : (wqs + ((long)b * 12 + hh - 12) * 768);
    float p = 0.f;
#pragma unroll
    for (int j = 0; j < 12; j++) p += qv[j] * vec[lane + 64 * j];
#pragma unroll
    for (int m = 32; m >= 1; m >>= 1) p += __shfl_xor(p, m);
    if (lane == 0) amu[((long)b * 24 + hh) * 1024 + qrow] = p;
  }
}

// ---------------------------------------------------------------------------
// Fused MFMA attention: ctx[q,d] = sum_n r(q,n) * V[n,d] per (b,h).
// A = R computed in-register (split rh/rl), B = V^T (pre-split bf16 h/l).
// Wave tile: 32 q (fi=0,1) x 64 d (fj=0..3), K = 256 n in 8 k-steps.
// 3 MFMA passes: rh*vh + rl*vh + rh*vl (rl*vl ~ 2^-34, dropped).
// Writes ctx directly as split-bf16 for the final MFMA GEMM.
// ---------------------------------------------------------------------------
__global__ __launch_bounds__(256) void attn_mfma(
    const __hip_bfloat16* __restrict__ Vth, const __hip_bfloat16* __restrict__ Vtl,
    const float* __restrict__ amu, const float* __restrict__ mubf,
    const float* __restrict__ sigbf, __hip_bfloat16* __restrict__ Ch,
    __hip_bfloat16* __restrict__ Cl) {
  const int qch = blockIdx.x, h = blockIdx.y, b = blockIdx.z;
  const int t = threadIdx.x;
  const int lane = t & 63, wave = t >> 6;
  const int r = lane & 15, g = lane >> 4;
  const int wq = wave * 32;
  __shared__ float s_mub[NB], s_sb2[NB];
  {
    float sb = sigbf[t];
    s_mub[t] = mubf[t];
    s_sb2[t] = sb * sb;
  }
  __syncthreads();

  // per-lane (mu, sig) for its two A-fragment rows: q = qch*128 + wq + fi*16 + r
  float mu_[2], sig_[2];
#pragma unroll
  for (int fi = 0; fi < 2; fi++) {
    int q = qch * 128 + wq + fi * 16 + r;
    float araw = amu[((long)b * 24 + h) * 1024 + q] * 0.125f;
    float sraw = amu[((long)b * 24 + 12 + h) * 1024 + q] * 0.125f;
    mu_[fi] = 1.f / (1.f + expf(-araw));
    sig_[fi] = fmaxf(sraw, 0.f) + log1pf(expf(-fabsf(sraw)));  // softplus
  }

  const __hip_bfloat16* vhb = Vth + ((long)b * 12 + h) * 16384;
  const __hip_bfloat16* vlb = Vtl + ((long)b * 12 + h) * 16384;

  f32x4 zero4 = {0.f, 0.f, 0.f, 0.f};
  f32x4 acc[2][4];
#pragma unroll
  for (int fi = 0; fi < 2; fi++)
#pragma unroll
    for (int fj = 0; fj < 4; fj++) acc[fi][fj] = zero4;

  for (int ks = 0; ks < 8; ks++) {
    // Build A fragments: r-values for n = ks*32 + g*8 + j (same k-map as B).
    bf16x8 rh[2], rl[2];
#pragma unroll
    for (int fi = 0; fi < 2; fi++) {
      float mu = mu_[fi], sg = sig_[fi];
#pragma unroll
      for (int j = 0; j < 8; j++) {
        int n = ks * 32 + g * 8 + j;
        float inv_s = rsqrtf(s_sb2[n] + sg);
        float tt = (mu - s_mub[n]) * inv_s;
        float rv = 0.3989422804014327f * inv_s *
                   exp2f(-0.7213475204444817f * tt * tt);
        __bf16 hi = (__bf16)rv;
        rh[fi][j] = hi;
        rl[fi][j] = (__bf16)(rv - (float)hi);  // split exact by construction
      }
    }
#pragma unroll
    for (int fj = 0; fj < 4; fj++) {
      long vo = (long)(fj * 16 + r) * 256 + ks * 32 + g * 8;
      bf16x8 vh = *(const bf16x8*)(vhb + vo);
      bf16x8 vl = *(const bf16x8*)(vlb + vo);
#pragma unroll
      for (int fi = 0; fi < 2; fi++) {
        acc[fi][fj] = __builtin_amdgcn_mfma_f32_16x16x32_bf16(
            rh[fi], vh, acc[fi][fj], 0, 0, 0);
        acc[fi][fj] = __builtin_amdgcn_mfma_f32_16x16x32_bf16(
            rl[fi], vh, acc[fi][fj], 0, 0, 0);
        acc[fi][fj] = __builtin_amdgcn_mfma_f32_16x16x32_bf16(
            rh[fi], vl, acc[fi][fj], 0, 0, 0);
      }
    }
  }

#pragma unroll
  for (int fi = 0; fi < 2; fi++)
#pragma unroll
    for (int fj = 0; fj < 4; fj++)
#pragma unroll
      for (int v = 0; v < 4; v++) {
        int q = qch * 128 + wq + fi * 16 + g * 4 + v;  // row = (lane>>4)*4+reg
        int d = fj * 16 + r;                            // col = lane&15
        long off = ((long)(b * SLEN + q)) * DM + h * HEAD + d;
        float f = acc[fi][fj][v];
        __hip_bfloat16 hh = __float2bfloat16(f);
        Ch[off] = hh;
        Cl[off] = __float2bfloat16(f - __bfloat162float(hh));
      }
}

// ---------------------------------------------------------------------------
extern "C" void kernel_launch(void* const* d_in, const int* in_sizes, int n_in,
                              void* d_out, int out_size, void* d_ws, size_t ws_size,
                              hipStream_t stream) {
  const void* x    = d_in[0];
  const void* q    = d_in[1];
  const void* Wq   = d_in[2];
  const void* Wk   = d_in[3];
  const void* Wv   = d_in[4];
  const void* Wo   = d_in[5];
  const void* wmu  = d_in[6];
  const void* wsig = d_in[7];
  const void* mub  = d_in[8];
  const void* sigb = d_in[9];
  const void* G    = d_in[10];

  int* flagp = (int*)d_ws;
  float* base = (float*)d_ws + 16;
  float* Wqf   = base;              // 589824
  float* Wkf   = Wqf + 589824;      // 589824
  float* wmuf  = Wkf + 589824;      // 256
  float* wsigf = wmuf + 256;        // 256
  float* mubf  = wsigf + 256;       // 256
  float* sigbf = mubf + 256;        // 256
  float* Bmat  = sigbf + 256;       // 1572864  [256, 6144] fp32
  float* values= Bmat + 1572864;    // 1572864  [B,H,256,64] fp32
  float* bmu   = values + 1572864;  // 6144
  float* bsig  = bmu + 6144;        // 6144
  float* kmu   = bsig + 6144;       // 6144
  float* ksig  = kmu + 6144;        // 6144
  float* wqm   = ksig + 6144;       // 73728
  float* wqs   = wqm + 73728;       // 73728
  float* amu   = wqs + 73728;       // 196608  [B,24,1024]
  // bf16 arrays (element counts; all 16B-aligned)
  __hip_bfloat16* Wvh = (__hip_bfloat16*)(amu + 196608);  // 589824
  __hip_bfloat16* Wvl = Wvh + 589824;   // 589824
  __hip_bfloat16* Woh = Wvl + 589824;   // 589824
  __hip_bfloat16* Wol = Woh + 589824;   // 589824
  __hip_bfloat16* Gth = Wol + 589824;   // 262144  [256,1024]
  __hip_bfloat16* Gtl = Gth + 262144;   // 262144
  __hip_bfloat16* Bh  = Gtl + 262144;   // 1572864 [256,6144]
  __hip_bfloat16* Bl  = Bh + 1572864;   // 1572864
  // XCh/XCl: holds x^T [6144,1024] for GEMM1, then reused as ctx-split
  // [8192,768] for GEMM3 (GEMM1 strictly precedes attn on the stream).
  __hip_bfloat16* XCh = Bl + 1572864;   // 6291456
  __hip_bfloat16* XCl = XCh + 6291456;  // 6291456
  __hip_bfloat16* Vth = XCl + 6291456;  // 1572864 [B,H,64,256] split V^T
  __hip_bfloat16* Vtl = Vth + 1572864;  // 1572864
  // total ~63 MB

  detect_dtype<<<1, 256, 0, stream>>>(x, flagp);

  // fp32 copies needed by the collapse chain
  convertk<<<2304, 256, 0, stream>>>(Wq, Wqf, 589824, flagp);
  convertk<<<2304, 256, 0, stream>>>(Wk, Wkf, 589824, flagp);
  convertk<<<1, 256, 0, stream>>>(wmu, wmuf, 256, flagp);
  convertk<<<1, 256, 0, stream>>>(wsig, wsigf, 256, flagp);
  convertk<<<1, 256, 0, stream>>>(mub, mubf, 256, flagp);
  convertk<<<1, 256, 0, stream>>>(sigb, sigbf, 256, flagp);

  // bf16-split operands for the MFMA GEMMs
  tsplit<<<dim3(4, 16), 256, 0, stream>>>(G, Gth, Gtl, 1024, 256, flagp);
  tsplit<<<dim3(96, 16), 256, 0, stream>>>(x, XCh, XCl, 1024, 6144, flagp);
  split4<<<576, 256, 0, stream>>>(Wv, Wvh, Wvl, 589824, flagp, 1);
  split4<<<576, 256, 0, stream>>>(Wo, Woh, Wol, 589824, flagp, 1);

  // GEMM1: Bmat[m,n] = sum_k Gt[m,k] * Xt[n,k]; M=256 N=6144 K=1024 -> fp32
  // ksplit=8 -> 768 blocks (3 blocks/CU) atomicAdd into zeroed Bmat.
  // bf16 inputs: pass 0 only (lossless — both lo buffers are exactly zero).
  zerok<<<1536, 256, 0, stream>>>(Bmat, 1572864);
  mfma_nt_lds<<<dim3(48, 2, 8), 256, 0, stream>>>(
      Gth, Gtl, XCh, XCl, Bmat, /*K=*/1024, /*lda=*/1024, /*ldb=*/1024,
      /*a_batch=*/0, /*c_batch=*/0, /*om=*/6144, /*oh=*/64, flagp, 0,
      /*pmask_bf=*/1, /*ksplit=*/8);

  split4<<<1536, 256, 0, stream>>>(Bmat, Bh, Bl, 1572864, flagp, 0);

  // GEMM2: values(z) = Bmat_z @ Wv^T -> [B,H,256,64] fp32 (bf16: skip Ah*Wl)
  // ksplit=8 -> 768 blocks, atomicAdd into zeroed values.
  zerok<<<1536, 256, 0, stream>>>(values, 1572864);
  mfma_nt_lds<<<dim3(6, 2, 64), 256, 0, stream>>>(
      Bh, Bl, Wvh, Wvl, values, /*K=*/768, /*lda=*/6144, /*ldb=*/768,
      /*a_batch=*/768, /*c_batch=*/196608, /*om=*/64, /*oh=*/16384, flagp, 0,
      /*pmask_bf=*/5, /*ksplit=*/8);

  // V^T split for MFMA attention
  vtsplit<<<dim3(4, 96), 256, 0, stream>>>(values, Vth, Vtl);

  // scores@w collapse chain: bmu/bsig -> kmu/ksig -> wqm/wqs -> amu
  bvec<<<48, 256, 0, stream>>>(Bmat, wmuf, wsigf, bmu, bsig);
  kvec<<<48, 256, 0, stream>>>(Wkf, bmu, bsig, kmu, ksig);
  wqvec<<<576, 256, 0, stream>>>(Wqf, kmu, ksig, wqm, wqs);
  amu_kernel<<<dim3(256, 8), 256, 0, stream>>>(q, wqm, wqs, amu, flagp);

  // fused MFMA attention -> ctx split-bf16 [8192,768] (into XCh/XCl)
  attn_mfma<<<dim3(8, 12, 8), 256, 0, stream>>>(
      Vth, Vtl, amu, mubf, sigbf, XCh, XCl);

  // GEMM3: out = ctx @ Wo^T; M=8192 N=768 K=768 (bf16: skip Ah*Wl pass)
  // 384 blocks already; direct store (dtype per flag).
  mfma_nt_lds<<<dim3(6, 64, 1), 256, 0, stream>>>(
      XCh, XCl, Woh, Wol, d_out, /*K=*/768, /*lda=*/768, /*ldb=*/768,
      /*a_batch=*/0, /*c_batch=*/0, /*om=*/768, /*oh=*/64, flagp, 1,
      /*pmask_bf=*/5, /*ksplit=*/1);
}